// Round 6
// baseline (278.503 us; speedup 1.0000x reference)
//
#include <hip/hip_runtime.h>

// Problem constants: B=8, N=1024, D_MODEL=512, H=8, HD=64
#define SCALE_ 0.125f
#define LN_EPS_ 1e-5f

typedef __attribute__((ext_vector_type(8))) short bf16x8;
typedef __attribute__((ext_vector_type(4))) float f32x4;

__device__ __forceinline__ ushort f2b(float f) {
  union { float f; unsigned u; } x; x.f = f;
  unsigned r = x.u + 0x7FFFu + ((x.u >> 16) & 1u);  // RNE
  return (ushort)(r >> 16);
}

__device__ __forceinline__ f32x4 mfma16(bf16x8 a, bf16x8 b, f32x4 c) {
  return __builtin_amdgcn_mfma_f32_16x16x32_bf16(a, b, c, 0, 0, 0);
}

// ---------------- K0: f32 [R][C] -> bf16 [C][R] (transpose-cast for weights)
__global__ __launch_bounds__(256) void cast_transpose(const float* __restrict__ src,
                                                      ushort* __restrict__ dst,
                                                      int R, int C) {
  __shared__ ushort t[64][65];
  const int tid = threadIdx.x;
  const int c0 = blockIdx.x * 64, r0 = blockIdx.y * 64;
  const int lr = tid >> 2, lc = (tid & 3) * 16;
#pragma unroll
  for (int u = 0; u < 4; ++u) {
    float4 v = *(const float4*)&src[(size_t)(r0 + lr) * C + c0 + lc + u * 4];
    t[lc + u * 4 + 0][lr] = f2b(v.x);
    t[lc + u * 4 + 1][lr] = f2b(v.y);
    t[lc + u * 4 + 2][lr] = f2b(v.z);
    t[lc + u * 4 + 3][lr] = f2b(v.w);
  }
  __syncthreads();
#pragma unroll
  for (int u = 0; u < 2; ++u) {
    bf16x8 o;
#pragma unroll
    for (int e = 0; e < 8; ++e) o[e] = (short)t[lr][lc + u * 8 + e];
    *(bf16x8*)&dst[(size_t)(c0 + lr) * R + r0 + lc + u * 8] = o;
  }
}

// ---------------- K1: qkv = x @ W_qkv + b. 128x128 tile, fused f32->bf16 cast of x.
// Outputs: q, k in (b,h,i,d) bf16; v TRANSPOSED as vt (b,h,d,i) bf16.
__global__ __launch_bounds__(256) void qkv_mfma(const float* __restrict__ x,
                                                const ushort* __restrict__ Wt,
                                                const float* __restrict__ bias,
                                                ushort* __restrict__ q,
                                                ushort* __restrict__ k,
                                                ushort* __restrict__ vt) {
  __shared__ ushort A[128][40];
  __shared__ ushort Bs[128][40];
  const int tid = threadIdx.x;
  const int n0 = blockIdx.x * 128;   // 12
  const int m0 = blockIdx.y * 128;   // 64
  const int lane = tid & 63, wid = tid >> 6;
  const int wr = wid >> 1, wc = wid & 1;
  const int lr = lane & 15, g4 = lane >> 4;
  const int sr = tid >> 1, sco = (tid & 1) * 16;
  f32x4 acc[4][4] = {};
  for (int k0 = 0; k0 < 512; k0 += 32) {
    {  // A: x f32 -> bf16 (16 elems/thread)
      const float4* xs = (const float4*)&x[(size_t)(m0 + sr) * 512 + k0 + sco];
      float4 v0 = xs[0], v1 = xs[1], v2 = xs[2], v3 = xs[3];
      bf16x8 p0, p1;
      p0[0] = (short)f2b(v0.x); p0[1] = (short)f2b(v0.y);
      p0[2] = (short)f2b(v0.z); p0[3] = (short)f2b(v0.w);
      p0[4] = (short)f2b(v1.x); p0[5] = (short)f2b(v1.y);
      p0[6] = (short)f2b(v1.z); p0[7] = (short)f2b(v1.w);
      p1[0] = (short)f2b(v2.x); p1[1] = (short)f2b(v2.y);
      p1[2] = (short)f2b(v2.z); p1[3] = (short)f2b(v2.w);
      p1[4] = (short)f2b(v3.x); p1[5] = (short)f2b(v3.y);
      p1[6] = (short)f2b(v3.z); p1[7] = (short)f2b(v3.w);
      *(bf16x8*)&A[sr][sco] = p0;
      *(bf16x8*)&A[sr][sco + 8] = p1;
    }
    {  // B: Wt [n][k] bf16, direct
      const bf16x8* wp = (const bf16x8*)&Wt[(size_t)(n0 + sr) * 512 + k0 + sco];
      *(bf16x8*)&Bs[sr][sco] = wp[0];
      *(bf16x8*)&Bs[sr][sco + 8] = wp[1];
    }
    __syncthreads();
    bf16x8 af[4], bf[4];
#pragma unroll
    for (int mr = 0; mr < 4; ++mr) af[mr] = *(bf16x8*)&A[wr * 64 + mr * 16 + lr][g4 * 8];
#pragma unroll
    for (int nr = 0; nr < 4; ++nr) bf[nr] = *(bf16x8*)&Bs[wc * 64 + nr * 16 + lr][g4 * 8];
#pragma unroll
    for (int mr = 0; mr < 4; ++mr)
#pragma unroll
      for (int nr = 0; nr < 4; ++nr) acc[mr][nr] = mfma16(af[mr], bf[nr], acc[mr][nr]);
    __syncthreads();
  }
  const int part = n0 >> 9;  // uniform per block (boundaries 512/1024 are 128-aligned)
#pragma unroll
  for (int mr = 0; mr < 4; ++mr)
#pragma unroll
    for (int nr = 0; nr < 4; ++nr) {
      const int n = n0 + wc * 64 + nr * 16 + lr;
      const int h = (n & 511) >> 6, d = n & 63;
      const float bb = bias[n];
#pragma unroll
      for (int r = 0; r < 4; ++r) {
        int token = m0 + wr * 64 + mr * 16 + g4 * 4 + r;
        int bi = token >> 10, ii = token & 1023;
        ushort valb = f2b(acc[mr][nr][r] + bb);
        if (part == 0)
          q[(((size_t)(bi * 8 + h) * 1024 + ii) * 64) + d] = valb;
        else if (part == 1)
          k[(((size_t)(bi * 8 + h) * 1024 + ii) * 64) + d] = valb;
        else
          vt[((size_t)(bi * 8 + h) * 64 + d) * 1024 + ii] = valb;
      }
    }
}

// ---------------- K2 (fused): QK^T -> softmax (2-pass recompute) -> mix -> LN
//                  -> attn write -> PV (V^T direct from global) -> pv (bf16)
// Block: (i0 = blockIdx.x*16, b), 512 threads = 8 waves, wave h owns head h.
// LDS: PM only (~19 KB) -> 2 blocks/CU. 2 barriers per jt.
__global__ __launch_bounds__(512) void attn_fused(const ushort* __restrict__ q,
                                                  const ushort* __restrict__ k,
                                                  const ushort* __restrict__ vt,
                                                  const float* __restrict__ rw,
                                                  const float* __restrict__ ln_g,
                                                  const float* __restrict__ ln_b,
                                                  float* __restrict__ attn,
                                                  ushort* __restrict__ pv) {
  __shared__ float PM[8][16][36];
  __shared__ float wsh[64];
  __shared__ float gsh[8], bsh[8];

  const int tid = threadIdx.x;
  const int lane = tid & 63;
  const int h = tid >> 6;
  const int i0 = blockIdx.x * 16;
  const int b = blockIdx.y;
  const int lr = lane & 15, g4 = lane >> 4;

  const ushort* qh = q + ((size_t)(b * 8 + h) * 1024 + i0) * 64;
  const ushort* kh = k + (size_t)(b * 8 + h) * 65536;
  const ushort* vth = vt + (size_t)(b * 8 + h) * 65536;

  if (tid < 64) wsh[tid] = rw[tid];
  if (tid < 8) { gsh[tid] = ln_g[tid]; bsh[tid] = ln_b[tid]; }

  bf16x8 qf[2];
#pragma unroll
  for (int ks = 0; ks < 2; ++ks)
    qf[ks] = *(const bf16x8*)&qh[(size_t)lr * 64 + ks * 32 + g4 * 8];

  // ---- Phase 0: softmax denominators entirely in registers
  float psum[4] = {0.f, 0.f, 0.f, 0.f};
  for (int jt = 0; jt < 32; ++jt) {
    const int j0 = jt * 32;
    f32x4 sa[2] = {};
#pragma unroll
    for (int nr = 0; nr < 2; ++nr)
#pragma unroll
      for (int ks = 0; ks < 2; ++ks) {
        bf16x8 kf = *(const bf16x8*)&kh[(size_t)(j0 + nr * 16 + lr) * 64 + ks * 32 + g4 * 8];
        sa[nr] = mfma16(qf[ks], kf, sa[nr]);
      }
#pragma unroll
    for (int nr = 0; nr < 2; ++nr)
#pragma unroll
      for (int r = 0; r < 4; ++r) psum[r] += __expf(sa[nr][r] * SCALE_);
  }
  float inv_[4];
#pragma unroll
  for (int r = 0; r < 4; ++r) {
    float s = psum[r];
#pragma unroll
    for (int off = 1; off <= 8; off <<= 1) s += __shfl_xor(s, off);
    inv_[r] = 1.0f / s;
  }

  // ---- Phase 1
  f32x4 oacc[4] = {};
  const int m_ii = tid >> 5, m_jj = tid & 31;

  for (int jt = 0; jt < 32; ++jt) {
    const int j0 = jt * 32;
    // recompute S, P = exp * inv -> PM[h]
    f32x4 sa[2] = {};
#pragma unroll
    for (int nr = 0; nr < 2; ++nr)
#pragma unroll
      for (int ks = 0; ks < 2; ++ks) {
        bf16x8 kf = *(const bf16x8*)&kh[(size_t)(j0 + nr * 16 + lr) * 64 + ks * 32 + g4 * 8];
        sa[nr] = mfma16(qf[ks], kf, sa[nr]);
      }
#pragma unroll
    for (int nr = 0; nr < 2; ++nr)
#pragma unroll
      for (int r = 0; r < 4; ++r)
        PM[h][g4 * 4 + r][nr * 16 + lr] = __expf(sa[nr][r] * SCALE_) * inv_[r];
    __syncthreads();  // B1: all heads' P ready

    // mix + LN: thread owns position (m_ii, m_jj), all 8 heads
    float ph[8];
#pragma unroll
    for (int h2 = 0; h2 < 8; ++h2) ph[h2] = PM[h2][m_ii][m_jj];
    float mixed[8];
#pragma unroll
    for (int k2 = 0; k2 < 8; ++k2) {
      float a = 0.f;
#pragma unroll
      for (int h2 = 0; h2 < 8; ++h2) a += ph[h2] * wsh[h2 * 8 + k2];
      mixed[k2] = a;
    }
    float mu = 0.f;
#pragma unroll
    for (int k2 = 0; k2 < 8; ++k2) mu += mixed[k2];
    mu *= 0.125f;
    float var = 0.f;
#pragma unroll
    for (int k2 = 0; k2 < 8; ++k2) { float d = mixed[k2] - mu; var += d * d; }
    var *= 0.125f;
    const float rs = rsqrtf(var + LN_EPS_);
    const size_t abase = ((size_t)(b * 8) << 20) + ((size_t)(i0 + m_ii) << 10) + j0 + m_jj;
#pragma unroll
    for (int k2 = 0; k2 < 8; ++k2) {
      float val = (mixed[k2] - mu) * rs * gsh[k2] + bsh[k2];
      attn[abase + ((size_t)k2 << 20)] = val;
      PM[k2][m_ii][m_jj] = val;  // in-place
    }
    __syncthreads();  // B2: LN'd PM ready

    // PV: O_h += PM[h] (16x32 -> bf16) @ V_h; V^T fragments direct from global (L2)
    float4 p0 = *(const float4*)&PM[h][lr][g4 * 8];
    float4 p1 = *(const float4*)&PM[h][lr][g4 * 8 + 4];
    bf16x8 pa;
    pa[0] = (short)f2b(p0.x); pa[1] = (short)f2b(p0.y);
    pa[2] = (short)f2b(p0.z); pa[3] = (short)f2b(p0.w);
    pa[4] = (short)f2b(p1.x); pa[5] = (short)f2b(p1.y);
    pa[6] = (short)f2b(p1.z); pa[7] = (short)f2b(p1.w);
#pragma unroll
    for (int nd = 0; nd < 4; ++nd) {
      bf16x8 vf = *(const bf16x8*)&vth[(size_t)(nd * 16 + lr) * 1024 + j0 + g4 * 8];
      oacc[nd] = mfma16(pa, vf, oacc[nd]);
    }
    // no trailing barrier: PM[h] next written only by wave h (S-stage),
    // cross-wave mix writes are guarded by next B1.
  }

  // write pv (bf16, (b,h,i,d))
  ushort* po = pv + ((size_t)(b * 8 + h) * 1024 + i0) * 64;
#pragma unroll
  for (int nd = 0; nd < 4; ++nd)
#pragma unroll
    for (int r = 0; r < 4; ++r)
      po[(size_t)(g4 * 4 + r) * 64 + nd * 16 + lr] = f2b(oacc[nd][r]);
}

// ---------------- K3: out = pv(b,n,(h d)) @ W_out + b_out. 128x128 tile.
__global__ __launch_bounds__(256) void out_mfma(const ushort* __restrict__ pvb,
                                                const ushort* __restrict__ Wt,
                                                const float* __restrict__ bias,
                                                float* __restrict__ out) {
  __shared__ ushort A[128][40];
  __shared__ ushort Bs[128][40];
  const int tid = threadIdx.x;
  const int n0 = blockIdx.x * 128;   // 4
  const int m0 = blockIdx.y * 128;   // 64
  const int lane = tid & 63, wid = tid >> 6;
  const int wr = wid >> 1, wc = wid & 1;
  const int lr = lane & 15, g4 = lane >> 4;
  const int sr = tid >> 1, sco = (tid & 1) * 16;
  f32x4 acc[4][4] = {};
  for (int k0 = 0; k0 < 512; k0 += 32) {
    {  // A: pv bf16 gathered as (token, f=(h,d))
      int token = m0 + sr;
      int bi = token >> 10, ii = token & 1023;
      int f = k0 + sco;
      int hh = f >> 6, d = f & 63;
      const bf16x8* src =
          (const bf16x8*)&pvb[(((size_t)(bi * 8 + hh)) * 1024 + ii) * 64 + d];
      *(bf16x8*)&A[sr][sco] = src[0];
      *(bf16x8*)&A[sr][sco + 8] = src[1];
    }
    {
      const bf16x8* wp = (const bf16x8*)&Wt[(size_t)(n0 + sr) * 512 + k0 + sco];
      *(bf16x8*)&Bs[sr][sco] = wp[0];
      *(bf16x8*)&Bs[sr][sco + 8] = wp[1];
    }
    __syncthreads();
    bf16x8 af[4], bf[4];
#pragma unroll
    for (int mr = 0; mr < 4; ++mr) af[mr] = *(bf16x8*)&A[wr * 64 + mr * 16 + lr][g4 * 8];
#pragma unroll
    for (int nr = 0; nr < 4; ++nr) bf[nr] = *(bf16x8*)&Bs[wc * 64 + nr * 16 + lr][g4 * 8];
#pragma unroll
    for (int mr = 0; mr < 4; ++mr)
#pragma unroll
      for (int nr = 0; nr < 4; ++nr) acc[mr][nr] = mfma16(af[mr], bf[nr], acc[mr][nr]);
    __syncthreads();
  }
#pragma unroll
  for (int mr = 0; mr < 4; ++mr)
#pragma unroll
    for (int nr = 0; nr < 4; ++nr) {
      const int n = n0 + wc * 64 + nr * 16 + lr;
      const float bb = bias[n];
#pragma unroll
      for (int r = 0; r < 4; ++r) {
        int token = m0 + wr * 64 + mr * 16 + g4 * 4 + r;
        out[(size_t)token * 512 + n] = acc[mr][nr][r] + bb;
      }
    }
}

extern "C" void kernel_launch(void* const* d_in, const int* in_sizes, int n_in,
                              void* d_out, int out_size, void* d_ws, size_t ws_size,
                              hipStream_t stream) {
  const float* x    = (const float*)d_in[0];
  const float* Wqkv = (const float*)d_in[1];
  const float* bqkv = (const float*)d_in[2];
  const float* rw   = (const float*)d_in[3];
  const float* lng  = (const float*)d_in[4];
  const float* lnb  = (const float*)d_in[5];
  const float* Wout = (const float*)d_in[6];
  const float* bout = (const float*)d_in[7];

  float* out  = (float*)d_out;
  float* attn = (float*)d_out + 4194304;

  // ws: q [0,8M), k [8,16M), vt [16,24M), pvb [24,32M), Wqkvt [32,33.5M), Woutt [33.5,34M)
  char* wsb = (char*)d_ws;
  ushort* q     = (ushort*)(wsb);
  ushort* k     = (ushort*)(wsb + (8u << 20));
  ushort* vt    = (ushort*)(wsb + (16u << 20));
  ushort* pvb   = (ushort*)(wsb + (24u << 20));
  ushort* Wqkvt = (ushort*)(wsb + (32u << 20));
  ushort* Woutt = (ushort*)(wsb + (33u << 20) + (1u << 19));

  cast_transpose<<<dim3(24, 8), 256, 0, stream>>>(Wqkv, Wqkvt, 512, 1536);
  cast_transpose<<<dim3(8, 8), 256, 0, stream>>>(Wout, Woutt, 512, 512);

  qkv_mfma<<<dim3(12, 64), 256, 0, stream>>>(x, Wqkvt, bqkv, q, k, vt);
  attn_fused<<<dim3(64, 8), 512, 0, stream>>>(q, k, vt, rw, lng, lnb, attn, pvb);
  out_mfma<<<dim3(4, 64), 256, 0, stream>>>(pvb, Woutt, bout, out);
}

// Round 7
// 251.452 us; speedup vs baseline: 1.1076x; 1.1076x over previous
//
#include <hip/hip_runtime.h>

// Problem constants: B=8, N=1024, D_MODEL=512, H=8, HD=64
#define SCALE_ 0.125f
#define LN_EPS_ 1e-5f

typedef __attribute__((ext_vector_type(8))) short bf16x8;
typedef __attribute__((ext_vector_type(4))) float f32x4;

__device__ __forceinline__ ushort f2b(float f) {
  union { float f; unsigned u; } x; x.f = f;
  unsigned r = x.u + 0x7FFFu + ((x.u >> 16) & 1u);  // RNE
  return (ushort)(r >> 16);
}

__device__ __forceinline__ f32x4 mfma16(bf16x8 a, bf16x8 b, f32x4 c) {
  return __builtin_amdgcn_mfma_f32_16x16x32_bf16(a, b, c, 0, 0, 0);
}

// LDS-only barrier: does NOT drain vmcnt, so global stores/loads stay in flight.
// Safe here: barriers only protect LDS (PM); attn global stores are never read.
__device__ __forceinline__ void bar_lds() {
  asm volatile("s_waitcnt lgkmcnt(0)\n\ts_barrier" ::: "memory");
  __builtin_amdgcn_sched_barrier(0);  // rule #18: pin code motion at the barrier
}

// ---------------- K0: f32 [R][C] -> bf16 [C][R] (transpose-cast for weights)
__global__ __launch_bounds__(256) void cast_transpose(const float* __restrict__ src,
                                                      ushort* __restrict__ dst,
                                                      int R, int C) {
  __shared__ ushort t[64][65];
  const int tid = threadIdx.x;
  const int c0 = blockIdx.x * 64, r0 = blockIdx.y * 64;
  const int lr = tid >> 2, lc = (tid & 3) * 16;
#pragma unroll
  for (int u = 0; u < 4; ++u) {
    float4 v = *(const float4*)&src[(size_t)(r0 + lr) * C + c0 + lc + u * 4];
    t[lc + u * 4 + 0][lr] = f2b(v.x);
    t[lc + u * 4 + 1][lr] = f2b(v.y);
    t[lc + u * 4 + 2][lr] = f2b(v.z);
    t[lc + u * 4 + 3][lr] = f2b(v.w);
  }
  __syncthreads();
#pragma unroll
  for (int u = 0; u < 2; ++u) {
    bf16x8 o;
#pragma unroll
    for (int e = 0; e < 8; ++e) o[e] = (short)t[lr][lc + u * 8 + e];
    *(bf16x8*)&dst[(size_t)(c0 + lr) * R + r0 + lc + u * 8] = o;
  }
}

// ---------------- K1: qkv = x @ W_qkv + b. 128x128 tile, fused f32->bf16 cast of x.
// Outputs: q, k in (b,h,i,d) bf16; v TRANSPOSED as vt (b,h,d,i) bf16.
__global__ __launch_bounds__(256) void qkv_mfma(const float* __restrict__ x,
                                                const ushort* __restrict__ Wt,
                                                const float* __restrict__ bias,
                                                ushort* __restrict__ q,
                                                ushort* __restrict__ k,
                                                ushort* __restrict__ vt) {
  __shared__ ushort A[128][40];
  __shared__ ushort Bs[128][40];
  const int tid = threadIdx.x;
  const int n0 = blockIdx.x * 128;
  const int m0 = blockIdx.y * 128;
  const int lane = tid & 63, wid = tid >> 6;
  const int wr = wid >> 1, wc = wid & 1;
  const int lr = lane & 15, g4 = lane >> 4;
  const int sr = tid >> 1, sco = (tid & 1) * 16;
  f32x4 acc[4][4] = {};
  for (int k0 = 0; k0 < 512; k0 += 32) {
    {
      const float4* xs = (const float4*)&x[(size_t)(m0 + sr) * 512 + k0 + sco];
      float4 v0 = xs[0], v1 = xs[1], v2 = xs[2], v3 = xs[3];
      bf16x8 p0, p1;
      p0[0] = (short)f2b(v0.x); p0[1] = (short)f2b(v0.y);
      p0[2] = (short)f2b(v0.z); p0[3] = (short)f2b(v0.w);
      p0[4] = (short)f2b(v1.x); p0[5] = (short)f2b(v1.y);
      p0[6] = (short)f2b(v1.z); p0[7] = (short)f2b(v1.w);
      p1[0] = (short)f2b(v2.x); p1[1] = (short)f2b(v2.y);
      p1[2] = (short)f2b(v2.z); p1[3] = (short)f2b(v2.w);
      p1[4] = (short)f2b(v3.x); p1[5] = (short)f2b(v3.y);
      p1[6] = (short)f2b(v3.z); p1[7] = (short)f2b(v3.w);
      *(bf16x8*)&A[sr][sco] = p0;
      *(bf16x8*)&A[sr][sco + 8] = p1;
    }
    {
      const bf16x8* wp = (const bf16x8*)&Wt[(size_t)(n0 + sr) * 512 + k0 + sco];
      *(bf16x8*)&Bs[sr][sco] = wp[0];
      *(bf16x8*)&Bs[sr][sco + 8] = wp[1];
    }
    __syncthreads();
    bf16x8 af[4], bf[4];
#pragma unroll
    for (int mr = 0; mr < 4; ++mr) af[mr] = *(bf16x8*)&A[wr * 64 + mr * 16 + lr][g4 * 8];
#pragma unroll
    for (int nr = 0; nr < 4; ++nr) bf[nr] = *(bf16x8*)&Bs[wc * 64 + nr * 16 + lr][g4 * 8];
#pragma unroll
    for (int mr = 0; mr < 4; ++mr)
#pragma unroll
      for (int nr = 0; nr < 4; ++nr) acc[mr][nr] = mfma16(af[mr], bf[nr], acc[mr][nr]);
    __syncthreads();
  }
  const int part = n0 >> 9;
#pragma unroll
  for (int mr = 0; mr < 4; ++mr)
#pragma unroll
    for (int nr = 0; nr < 4; ++nr) {
      const int n = n0 + wc * 64 + nr * 16 + lr;
      const int h = (n & 511) >> 6, d = n & 63;
      const float bb = bias[n];
#pragma unroll
      for (int r = 0; r < 4; ++r) {
        int token = m0 + wr * 64 + mr * 16 + g4 * 4 + r;
        int bi = token >> 10, ii = token & 1023;
        ushort valb = f2b(acc[mr][nr][r] + bb);
        if (part == 0)
          q[(((size_t)(bi * 8 + h) * 1024 + ii) * 64) + d] = valb;
        else if (part == 1)
          k[(((size_t)(bi * 8 + h) * 1024 + ii) * 64) + d] = valb;
        else
          vt[((size_t)(bi * 8 + h) * 64 + d) * 1024 + ii] = valb;
      }
    }
}

// ---------------- K2 (fused): QK^T -> softmax (2-pass recompute) -> mix -> LN
//                  -> attn NT-write -> PV -> pv (bf16)
// Block: (i0 = blockIdx.x*16, b), 512 threads = 8 waves, wave h owns head h.
// lgkm-only barriers (stores never drained in-loop); K 1-iter reg prefetch;
// V issued pre-B1, consumed post-B2.
__global__ __launch_bounds__(512, 4) void attn_fused(const ushort* __restrict__ q,
                                                     const ushort* __restrict__ k,
                                                     const ushort* __restrict__ vt,
                                                     const float* __restrict__ rw,
                                                     const float* __restrict__ ln_g,
                                                     const float* __restrict__ ln_b,
                                                     float* __restrict__ attn,
                                                     ushort* __restrict__ pv) {
  __shared__ float PM[8][16][36];
  __shared__ float wsh[64];
  __shared__ float gsh[8], bsh[8];

  const int tid = threadIdx.x;
  const int lane = tid & 63;
  const int h = tid >> 6;
  const int i0 = blockIdx.x * 16;
  const int b = blockIdx.y;
  const int lr = lane & 15, g4 = lane >> 4;

  const ushort* qh = q + ((size_t)(b * 8 + h) * 1024 + i0) * 64;
  const ushort* kh = k + (size_t)(b * 8 + h) * 65536;
  const ushort* vth = vt + (size_t)(b * 8 + h) * 65536;

  if (tid < 64) wsh[tid] = rw[tid];
  if (tid < 8) { gsh[tid] = ln_g[tid]; bsh[tid] = ln_b[tid]; }

  bf16x8 qf[2];
#pragma unroll
  for (int ks = 0; ks < 2; ++ks)
    qf[ks] = *(const bf16x8*)&qh[(size_t)lr * 64 + ks * 32 + g4 * 8];

  // ---- Phase 0: softmax denominators (reg-only), K double-buffered
  float psum[4] = {0.f, 0.f, 0.f, 0.f};
  {
    bf16x8 kc[4], kn[4];
#pragma unroll
    for (int nr = 0; nr < 2; ++nr)
#pragma unroll
      for (int ks = 0; ks < 2; ++ks)
        kc[nr * 2 + ks] = *(const bf16x8*)&kh[(size_t)(nr * 16 + lr) * 64 + ks * 32 + g4 * 8];
    for (int jt = 0; jt < 32; ++jt) {
      const int j0n = ((jt + 1) & 31) * 32;
#pragma unroll
      for (int nr = 0; nr < 2; ++nr)
#pragma unroll
        for (int ks = 0; ks < 2; ++ks)
          kn[nr * 2 + ks] =
              *(const bf16x8*)&kh[(size_t)(j0n + nr * 16 + lr) * 64 + ks * 32 + g4 * 8];
      f32x4 sa[2] = {};
      sa[0] = mfma16(qf[0], kc[0], sa[0]);
      sa[0] = mfma16(qf[1], kc[1], sa[0]);
      sa[1] = mfma16(qf[0], kc[2], sa[1]);
      sa[1] = mfma16(qf[1], kc[3], sa[1]);
#pragma unroll
      for (int nr = 0; nr < 2; ++nr)
#pragma unroll
        for (int r = 0; r < 4; ++r) psum[r] += __expf(sa[nr][r] * SCALE_);
#pragma unroll
      for (int i = 0; i < 4; ++i) kc[i] = kn[i];
    }
  }
  float inv_[4];
#pragma unroll
  for (int r = 0; r < 4; ++r) {
    float s = psum[r];
#pragma unroll
    for (int off = 1; off <= 8; off <<= 1) s += __shfl_xor(s, off);
    inv_[r] = 1.0f / s;
  }

  // ---- Phase 1
  f32x4 oacc[4] = {};
  const int m_ii = tid >> 5, m_jj = tid & 31;

  bf16x8 kc[4], kn[4];
#pragma unroll
  for (int nr = 0; nr < 2; ++nr)
#pragma unroll
    for (int ks = 0; ks < 2; ++ks)
      kc[nr * 2 + ks] = *(const bf16x8*)&kh[(size_t)(nr * 16 + lr) * 64 + ks * 32 + g4 * 8];

  for (int jt = 0; jt < 32; ++jt) {
    const int j0 = jt * 32;
    const int j0n = ((jt + 1) & 31) * 32;
    // prefetch next K (older than this iteration's stores -> counted vmcnt skips them)
#pragma unroll
    for (int nr = 0; nr < 2; ++nr)
#pragma unroll
      for (int ks = 0; ks < 2; ++ks)
        kn[nr * 2 + ks] =
            *(const bf16x8*)&kh[(size_t)(j0n + nr * 16 + lr) * 64 + ks * 32 + g4 * 8];

    // S recompute from kc, P = exp*inv -> PM[h]
    f32x4 sa[2] = {};
    sa[0] = mfma16(qf[0], kc[0], sa[0]);
    sa[0] = mfma16(qf[1], kc[1], sa[0]);
    sa[1] = mfma16(qf[0], kc[2], sa[1]);
    sa[1] = mfma16(qf[1], kc[3], sa[1]);
#pragma unroll
    for (int nr = 0; nr < 2; ++nr)
#pragma unroll
      for (int r = 0; r < 4; ++r)
        PM[h][g4 * 4 + r][nr * 16 + lr] = __expf(sa[nr][r] * SCALE_) * inv_[r];

    // issue V loads for THIS iteration now (pre-B1): latency hides under mix
    bf16x8 vc[4];
#pragma unroll
    for (int nd = 0; nd < 4; ++nd)
      vc[nd] = *(const bf16x8*)&vth[(size_t)(nd * 16 + lr) * 1024 + j0 + g4 * 8];

    bar_lds();  // B1: all heads' P visible

    // mix + LN: thread owns position (m_ii, m_jj), all 8 heads
    float ph[8];
#pragma unroll
    for (int h2 = 0; h2 < 8; ++h2) ph[h2] = PM[h2][m_ii][m_jj];
    float mixed[8];
#pragma unroll
    for (int k2 = 0; k2 < 8; ++k2) {
      float a = 0.f;
#pragma unroll
      for (int h2 = 0; h2 < 8; ++h2) a += ph[h2] * wsh[h2 * 8 + k2];
      mixed[k2] = a;
    }
    float mu = 0.f;
#pragma unroll
    for (int k2 = 0; k2 < 8; ++k2) mu += mixed[k2];
    mu *= 0.125f;
    float var = 0.f;
#pragma unroll
    for (int k2 = 0; k2 < 8; ++k2) { float d = mixed[k2] - mu; var += d * d; }
    var *= 0.125f;
    const float rs = rsqrtf(var + LN_EPS_);
    const size_t abase = ((size_t)(b * 8) << 20) + ((size_t)(i0 + m_ii) << 10) + j0 + m_jj;
#pragma unroll
    for (int k2 = 0; k2 < 8; ++k2) {
      float val = (mixed[k2] - mu) * rs * gsh[k2] + bsh[k2];
      __builtin_nontemporal_store(val, &attn[abase + ((size_t)k2 << 20)]);
      PM[k2][m_ii][m_jj] = val;  // in-place
    }

    bar_lds();  // B2: LN'd PM visible

    // PV: O_h += PM[h] (16x32 -> bf16) @ V_h (from vc regs)
    float4 p0 = *(const float4*)&PM[h][lr][g4 * 8];
    float4 p1 = *(const float4*)&PM[h][lr][g4 * 8 + 4];
    bf16x8 pa;
    pa[0] = (short)f2b(p0.x); pa[1] = (short)f2b(p0.y);
    pa[2] = (short)f2b(p0.z); pa[3] = (short)f2b(p0.w);
    pa[4] = (short)f2b(p1.x); pa[5] = (short)f2b(p1.y);
    pa[6] = (short)f2b(p1.z); pa[7] = (short)f2b(p1.w);
#pragma unroll
    for (int nd = 0; nd < 4; ++nd) oacc[nd] = mfma16(pa, vc[nd], oacc[nd]);

#pragma unroll
    for (int i = 0; i < 4; ++i) kc[i] = kn[i];
  }

  // write pv (bf16, (b,h,i,d))
  ushort* po = pv + ((size_t)(b * 8 + h) * 1024 + i0) * 64;
#pragma unroll
  for (int nd = 0; nd < 4; ++nd)
#pragma unroll
    for (int r = 0; r < 4; ++r)
      po[(size_t)(g4 * 4 + r) * 64 + nd * 16 + lr] = f2b(oacc[nd][r]);
}

// ---------------- K3: out = pv(b,n,(h d)) @ W_out + b_out. 128x128 tile.
__global__ __launch_bounds__(256) void out_mfma(const ushort* __restrict__ pvb,
                                                const ushort* __restrict__ Wt,
                                                const float* __restrict__ bias,
                                                float* __restrict__ out) {
  __shared__ ushort A[128][40];
  __shared__ ushort Bs[128][40];
  const int tid = threadIdx.x;
  const int n0 = blockIdx.x * 128;
  const int m0 = blockIdx.y * 128;
  const int lane = tid & 63, wid = tid >> 6;
  const int wr = wid >> 1, wc = wid & 1;
  const int lr = lane & 15, g4 = lane >> 4;
  const int sr = tid >> 1, sco = (tid & 1) * 16;
  f32x4 acc[4][4] = {};
  for (int k0 = 0; k0 < 512; k0 += 32) {
    {
      int token = m0 + sr;
      int bi = token >> 10, ii = token & 1023;
      int f = k0 + sco;
      int hh = f >> 6, d = f & 63;
      const bf16x8* src =
          (const bf16x8*)&pvb[(((size_t)(bi * 8 + hh)) * 1024 + ii) * 64 + d];
      *(bf16x8*)&A[sr][sco] = src[0];
      *(bf16x8*)&A[sr][sco + 8] = src[1];
    }
    {
      const bf16x8* wp = (const bf16x8*)&Wt[(size_t)(n0 + sr) * 512 + k0 + sco];
      *(bf16x8*)&Bs[sr][sco] = wp[0];
      *(bf16x8*)&Bs[sr][sco + 8] = wp[1];
    }
    __syncthreads();
    bf16x8 af[4], bf[4];
#pragma unroll
    for (int mr = 0; mr < 4; ++mr) af[mr] = *(bf16x8*)&A[wr * 64 + mr * 16 + lr][g4 * 8];
#pragma unroll
    for (int nr = 0; nr < 4; ++nr) bf[nr] = *(bf16x8*)&Bs[wc * 64 + nr * 16 + lr][g4 * 8];
#pragma unroll
    for (int mr = 0; mr < 4; ++mr)
#pragma unroll
      for (int nr = 0; nr < 4; ++nr) acc[mr][nr] = mfma16(af[mr], bf[nr], acc[mr][nr]);
    __syncthreads();
  }
#pragma unroll
  for (int mr = 0; mr < 4; ++mr)
#pragma unroll
    for (int nr = 0; nr < 4; ++nr) {
      const int n = n0 + wc * 64 + nr * 16 + lr;
      const float bb = bias[n];
#pragma unroll
      for (int r = 0; r < 4; ++r) {
        int token = m0 + wr * 64 + mr * 16 + g4 * 4 + r;
        out[(size_t)token * 512 + n] = acc[mr][nr][r] + bb;
      }
    }
}

extern "C" void kernel_launch(void* const* d_in, const int* in_sizes, int n_in,
                              void* d_out, int out_size, void* d_ws, size_t ws_size,
                              hipStream_t stream) {
  const float* x    = (const float*)d_in[0];
  const float* Wqkv = (const float*)d_in[1];
  const float* bqkv = (const float*)d_in[2];
  const float* rw   = (const float*)d_in[3];
  const float* lng  = (const float*)d_in[4];
  const float* lnb  = (const float*)d_in[5];
  const float* Wout = (const float*)d_in[6];
  const float* bout = (const float*)d_in[7];

  float* out  = (float*)d_out;
  float* attn = (float*)d_out + 4194304;

  // ws: q [0,8M), k [8,16M), vt [16,24M), pvb [24,32M), Wqkvt [32,33.5M), Woutt [33.5,34M)
  char* wsb = (char*)d_ws;
  ushort* q     = (ushort*)(wsb);
  ushort* k     = (ushort*)(wsb + (8u << 20));
  ushort* vt    = (ushort*)(wsb + (16u << 20));
  ushort* pvb   = (ushort*)(wsb + (24u << 20));
  ushort* Wqkvt = (ushort*)(wsb + (32u << 20));
  ushort* Woutt = (ushort*)(wsb + (33u << 20) + (1u << 19));

  cast_transpose<<<dim3(24, 8), 256, 0, stream>>>(Wqkv, Wqkvt, 512, 1536);
  cast_transpose<<<dim3(8, 8), 256, 0, stream>>>(Wout, Woutt, 512, 512);

  qkv_mfma<<<dim3(12, 64), 256, 0, stream>>>(x, Wqkvt, bqkv, q, k, vt);
  attn_fused<<<dim3(64, 8), 512, 0, stream>>>(q, k, vt, rw, lng, lnb, attn, pvb);
  out_mfma<<<dim3(4, 64), 256, 0, stream>>>(pvb, Woutt, bout, out);
}

// Round 9
// 183.605 us; speedup vs baseline: 1.5169x; 1.3695x over previous
//
#include <hip/hip_runtime.h>

// Problem constants: B=8, N=1024, D_MODEL=512, H=8, HD=64
#define SCALE_ 0.125f
#define LN_EPS_ 1e-5f

typedef __attribute__((ext_vector_type(8))) short bf16x8;
typedef __attribute__((ext_vector_type(4))) float f32x4;

__device__ __forceinline__ ushort f2b(float f) {
  union { float f; unsigned u; } x; x.f = f;
  unsigned r = x.u + 0x7FFFu + ((x.u >> 16) & 1u);  // RNE
  return (ushort)(r >> 16);
}

__device__ __forceinline__ f32x4 mfma16(bf16x8 a, bf16x8 b, f32x4 c) {
  return __builtin_amdgcn_mfma_f32_16x16x32_bf16(a, b, c, 0, 0, 0);
}

// LDS-only barrier: does NOT drain vmcnt (global stores/loads stay in flight).
// Safe: barriers protect only LDS (PM); attn global stores are never re-read.
__device__ __forceinline__ void bar_lds() {
  asm volatile("s_waitcnt lgkmcnt(0)\n\ts_barrier" ::: "memory");
  __builtin_amdgcn_sched_barrier(0);
}

// ---------------- K0: f32 [R][C] -> bf16 [C][R] (transpose-cast for weights)
__global__ __launch_bounds__(256) void cast_transpose(const float* __restrict__ src,
                                                      ushort* __restrict__ dst,
                                                      int R, int C) {
  __shared__ ushort t[64][65];
  const int tid = threadIdx.x;
  const int c0 = blockIdx.x * 64, r0 = blockIdx.y * 64;
  const int lr = tid >> 2, lc = (tid & 3) * 16;
#pragma unroll
  for (int u = 0; u < 4; ++u) {
    float4 v = *(const float4*)&src[(size_t)(r0 + lr) * C + c0 + lc + u * 4];
    t[lc + u * 4 + 0][lr] = f2b(v.x);
    t[lc + u * 4 + 1][lr] = f2b(v.y);
    t[lc + u * 4 + 2][lr] = f2b(v.z);
    t[lc + u * 4 + 3][lr] = f2b(v.w);
  }
  __syncthreads();
#pragma unroll
  for (int u = 0; u < 2; ++u) {
    bf16x8 o;
#pragma unroll
    for (int e = 0; e < 8; ++e) o[e] = (short)t[lr][lc + u * 8 + e];
    *(bf16x8*)&dst[(size_t)(c0 + lr) * R + r0 + lc + u * 8] = o;
  }
}

// ---------------- K1: qkv = x @ W_qkv + b. 128x128 tile, fused f32->bf16 cast of x.
// Outputs: q, k in (b,h,i,d) bf16; v TRANSPOSED as vt (b,h,d,i) bf16.
__global__ __launch_bounds__(256) void qkv_mfma(const float* __restrict__ x,
                                                const ushort* __restrict__ Wt,
                                                const float* __restrict__ bias,
                                                ushort* __restrict__ q,
                                                ushort* __restrict__ k,
                                                ushort* __restrict__ vt) {
  __shared__ ushort A[128][40];
  __shared__ ushort Bs[128][40];
  const int tid = threadIdx.x;
  const int n0 = blockIdx.x * 128;
  const int m0 = blockIdx.y * 128;
  const int lane = tid & 63, wid = tid >> 6;
  const int wr = wid >> 1, wc = wid & 1;
  const int lr = lane & 15, g4 = lane >> 4;
  const int sr = tid >> 1, sco = (tid & 1) * 16;
  f32x4 acc[4][4] = {};
  for (int k0 = 0; k0 < 512; k0 += 32) {
    {
      const float4* xs = (const float4*)&x[(size_t)(m0 + sr) * 512 + k0 + sco];
      float4 v0 = xs[0], v1 = xs[1], v2 = xs[2], v3 = xs[3];
      bf16x8 p0, p1;
      p0[0] = (short)f2b(v0.x); p0[1] = (short)f2b(v0.y);
      p0[2] = (short)f2b(v0.z); p0[3] = (short)f2b(v0.w);
      p0[4] = (short)f2b(v1.x); p0[5] = (short)f2b(v1.y);
      p0[6] = (short)f2b(v1.z); p0[7] = (short)f2b(v1.w);
      p1[0] = (short)f2b(v2.x); p1[1] = (short)f2b(v2.y);
      p1[2] = (short)f2b(v2.z); p1[3] = (short)f2b(v2.w);
      p1[4] = (short)f2b(v3.x); p1[5] = (short)f2b(v3.y);
      p1[6] = (short)f2b(v3.z); p1[7] = (short)f2b(v3.w);
      *(bf16x8*)&A[sr][sco] = p0;
      *(bf16x8*)&A[sr][sco + 8] = p1;
    }
    {
      const bf16x8* wp = (const bf16x8*)&Wt[(size_t)(n0 + sr) * 512 + k0 + sco];
      *(bf16x8*)&Bs[sr][sco] = wp[0];
      *(bf16x8*)&Bs[sr][sco + 8] = wp[1];
    }
    __syncthreads();
    bf16x8 af[4], bf[4];
#pragma unroll
    for (int mr = 0; mr < 4; ++mr) af[mr] = *(bf16x8*)&A[wr * 64 + mr * 16 + lr][g4 * 8];
#pragma unroll
    for (int nr = 0; nr < 4; ++nr) bf[nr] = *(bf16x8*)&Bs[wc * 64 + nr * 16 + lr][g4 * 8];
#pragma unroll
    for (int mr = 0; mr < 4; ++mr)
#pragma unroll
      for (int nr = 0; nr < 4; ++nr) acc[mr][nr] = mfma16(af[mr], bf[nr], acc[mr][nr]);
    __syncthreads();
  }
  const int part = n0 >> 9;
#pragma unroll
  for (int mr = 0; mr < 4; ++mr)
#pragma unroll
    for (int nr = 0; nr < 4; ++nr) {
      const int n = n0 + wc * 64 + nr * 16 + lr;
      const int h = (n & 511) >> 6, d = n & 63;
      const float bb = bias[n];
#pragma unroll
      for (int r = 0; r < 4; ++r) {
        int token = m0 + wr * 64 + mr * 16 + g4 * 4 + r;
        int bi = token >> 10, ii = token & 1023;
        ushort valb = f2b(acc[mr][nr][r] + bb);
        if (part == 0)
          q[(((size_t)(bi * 8 + h) * 1024 + ii) * 64) + d] = valb;
        else if (part == 1)
          k[(((size_t)(bi * 8 + h) * 1024 + ii) * 64) + d] = valb;
        else
          vt[((size_t)(bi * 8 + h) * 64 + d) * 1024 + ii] = valb;
      }
    }
}

// ---------------- K2 (fused): QK^T -> softmax (2-pass recompute) -> mix -> LN
//                  -> attn NT-write (f32x4) -> PV -> pv (bf16)
// QBLK=32 rows/block, 256 blocks, 8 waves (wave h = head h). 2 lgkm-only
// barriers per jt. XCD-swizzled so each XCD works one b (K/V 2MB < 4MB L2).
__global__ __launch_bounds__(512, 2) void attn_fused(const ushort* __restrict__ q,
                                                     const ushort* __restrict__ k,
                                                     const ushort* __restrict__ vt,
                                                     const float* __restrict__ rw,
                                                     const float* __restrict__ ln_g,
                                                     const float* __restrict__ ln_b,
                                                     float* __restrict__ attn,
                                                     ushort* __restrict__ pv) {
  __shared__ float PM[8][32][36];
  __shared__ float wsh[64];
  __shared__ float gsh[8], bsh[8];

  const int tid = threadIdx.x;
  const int lane = tid & 63;
  const int h = tid >> 6;
  // bijective XCD swizzle (256 blocks, 8 XCDs): XCD c handles orig [c*32,(c+1)*32) = one b
  const int obid = ((blockIdx.x & 7) << 5) + (blockIdx.x >> 3);
  const int i0 = (obid & 31) * 32;
  const int b = obid >> 5;
  const int lr = lane & 15, g4 = lane >> 4;

  const ushort* qh = q + ((size_t)(b * 8 + h) * 1024 + i0) * 64;
  const ushort* kh = k + (size_t)(b * 8 + h) * 65536;
  const ushort* vth = vt + (size_t)(b * 8 + h) * 65536;

  if (tid < 64) wsh[tid] = rw[tid];
  if (tid < 8) { gsh[tid] = ln_g[tid]; bsh[tid] = ln_b[tid]; }

  // Q fragments: rows mr*16+lr, k-slices ks*32 + g4*8
  bf16x8 qf[2][2];
#pragma unroll
  for (int mr = 0; mr < 2; ++mr)
#pragma unroll
    for (int ks = 0; ks < 2; ++ks)
      qf[mr][ks] = *(const bf16x8*)&qh[(size_t)(mr * 16 + lr) * 64 + ks * 32 + g4 * 8];

  // ---- Phase 0: softmax denominators (registers only), K double-buffered
  float psum[2][4] = {};
  {
    bf16x8 kc[4], kn[4];
#pragma unroll
    for (int nr = 0; nr < 2; ++nr)
#pragma unroll
      for (int ks = 0; ks < 2; ++ks)
        kc[nr * 2 + ks] = *(const bf16x8*)&kh[(size_t)(nr * 16 + lr) * 64 + ks * 32 + g4 * 8];
    for (int jt = 0; jt < 32; ++jt) {
      const int j0n = ((jt + 1) & 31) * 32;
#pragma unroll
      for (int nr = 0; nr < 2; ++nr)
#pragma unroll
        for (int ks = 0; ks < 2; ++ks)
          kn[nr * 2 + ks] =
              *(const bf16x8*)&kh[(size_t)(j0n + nr * 16 + lr) * 64 + ks * 32 + g4 * 8];
      f32x4 sa[2][2] = {};
#pragma unroll
      for (int mr = 0; mr < 2; ++mr)
#pragma unroll
        for (int nr = 0; nr < 2; ++nr) {
          sa[mr][nr] = mfma16(qf[mr][0], kc[nr * 2 + 0], sa[mr][nr]);
          sa[mr][nr] = mfma16(qf[mr][1], kc[nr * 2 + 1], sa[mr][nr]);
        }
#pragma unroll
      for (int mr = 0; mr < 2; ++mr)
#pragma unroll
        for (int nr = 0; nr < 2; ++nr)
#pragma unroll
          for (int r = 0; r < 4; ++r) psum[mr][r] += __expf(sa[mr][nr][r] * SCALE_);
#pragma unroll
      for (int i = 0; i < 4; ++i) kc[i] = kn[i];
    }
  }
  float inv_[2][4];
#pragma unroll
  for (int mr = 0; mr < 2; ++mr)
#pragma unroll
    for (int r = 0; r < 4; ++r) {
      float s = psum[mr][r];
#pragma unroll
      for (int off = 1; off <= 8; off <<= 1) s += __shfl_xor(s, off);
      inv_[mr][r] = 1.0f / s;
    }

  // ---- Phase 1
  f32x4 oacc[2][4] = {};
  // mix ownership: pair = tid&1 selects 4 heads; chunk owns (m_ii, m_jj..m_jj+3)
  const int pair = tid & 1, chunk = tid >> 1;
  const int m_ii = chunk >> 3, m_jj = (chunk & 7) * 4;
  const int k2base = pair * 4;

  bf16x8 kc[4], kn[4];
#pragma unroll
  for (int nr = 0; nr < 2; ++nr)
#pragma unroll
    for (int ks = 0; ks < 2; ++ks)
      kc[nr * 2 + ks] = *(const bf16x8*)&kh[(size_t)(nr * 16 + lr) * 64 + ks * 32 + g4 * 8];

  for (int jt = 0; jt < 32; ++jt) {
    const int j0 = jt * 32;
    const int j0n = ((jt + 1) & 31) * 32;
    // prefetch next K tile
#pragma unroll
    for (int nr = 0; nr < 2; ++nr)
#pragma unroll
      for (int ks = 0; ks < 2; ++ks)
        kn[nr * 2 + ks] =
            *(const bf16x8*)&kh[(size_t)(j0n + nr * 16 + lr) * 64 + ks * 32 + g4 * 8];

    // recompute S, P = exp*inv -> PM[h]
    f32x4 sa[2][2] = {};
#pragma unroll
    for (int mr = 0; mr < 2; ++mr)
#pragma unroll
      for (int nr = 0; nr < 2; ++nr) {
        sa[mr][nr] = mfma16(qf[mr][0], kc[nr * 2 + 0], sa[mr][nr]);
        sa[mr][nr] = mfma16(qf[mr][1], kc[nr * 2 + 1], sa[mr][nr]);
      }
#pragma unroll
    for (int mr = 0; mr < 2; ++mr)
#pragma unroll
      for (int nr = 0; nr < 2; ++nr)
#pragma unroll
        for (int r = 0; r < 4; ++r)
          PM[h][mr * 16 + g4 * 4 + r][nr * 16 + lr] =
              __expf(sa[mr][nr][r] * SCALE_) * inv_[mr][r];

    // V loads for this iteration (pre-B1, consumed post-B2; older than stores)
    bf16x8 vc[4];
#pragma unroll
    for (int nd = 0; nd < 4; ++nd)
      vc[nd] = *(const bf16x8*)&vth[(size_t)(nd * 16 + lr) * 1024 + j0 + g4 * 8];

    bar_lds();  // B1: all heads' P visible

    // mix + LN (float4, head-split across lane pairs), in-place PM update
    float4 ph[8];
#pragma unroll
    for (int h2 = 0; h2 < 8; ++h2) ph[h2] = *(const float4*)&PM[h2][m_ii][m_jj];
    float mixed[4][4];
#pragma unroll
    for (int k2l = 0; k2l < 4; ++k2l) {
      float a0 = 0.f, a1 = 0.f, a2 = 0.f, a3 = 0.f;
#pragma unroll
      for (int h2 = 0; h2 < 8; ++h2) {
        float w = wsh[h2 * 8 + k2base + k2l];
        a0 += ph[h2].x * w; a1 += ph[h2].y * w;
        a2 += ph[h2].z * w; a3 += ph[h2].w * w;
      }
      mixed[k2l][0] = a0; mixed[k2l][1] = a1; mixed[k2l][2] = a2; mixed[k2l][3] = a3;
    }
    float mu[4], rs_[4];
#pragma unroll
    for (int e = 0; e < 4; ++e) {
      float mp = mixed[0][e] + mixed[1][e] + mixed[2][e] + mixed[3][e];
      mu[e] = (mp + __shfl_xor(mp, 1)) * 0.125f;
    }
#pragma unroll
    for (int e = 0; e < 4; ++e) {
      float vp = 0.f;
#pragma unroll
      for (int k2l = 0; k2l < 4; ++k2l) {
        float d = mixed[k2l][e] - mu[e];
        vp += d * d;
      }
      float var = (vp + __shfl_xor(vp, 1)) * 0.125f;
      rs_[e] = rsqrtf(var + LN_EPS_);
    }
#pragma unroll
    for (int k2l = 0; k2l < 4; ++k2l) {
      int k2 = k2base + k2l;
      float g = gsh[k2], be = bsh[k2];
      f32x4 o;
      o[0] = (mixed[k2l][0] - mu[0]) * rs_[0] * g + be;
      o[1] = (mixed[k2l][1] - mu[1]) * rs_[1] * g + be;
      o[2] = (mixed[k2l][2] - mu[2]) * rs_[2] * g + be;
      o[3] = (mixed[k2l][3] - mu[3]) * rs_[3] * g + be;
      __builtin_nontemporal_store(
          o, (f32x4*)&attn[((size_t)(b * 8 + k2) << 20) + ((size_t)(i0 + m_ii) << 10) +
                           j0 + m_jj]);
      *(f32x4*)&PM[k2][m_ii][m_jj] = o;  // in-place (position owned by this pair)
    }

    bar_lds();  // B2: LN'd PM visible

    // PV: O_h += PM[h] (32x32 -> bf16) @ V_h (vc regs)
    bf16x8 pa[2];
#pragma unroll
    for (int mr = 0; mr < 2; ++mr) {
      const float* pr = &PM[h][mr * 16 + lr][g4 * 8];
      float4 p0 = *(const float4*)&pr[0];
      float4 p1 = *(const float4*)&pr[4];
      bf16x8 t;
      t[0] = (short)f2b(p0.x); t[1] = (short)f2b(p0.y);
      t[2] = (short)f2b(p0.z); t[3] = (short)f2b(p0.w);
      t[4] = (short)f2b(p1.x); t[5] = (short)f2b(p1.y);
      t[6] = (short)f2b(p1.z); t[7] = (short)f2b(p1.w);
      pa[mr] = t;
    }
#pragma unroll
    for (int nd = 0; nd < 4; ++nd) {
      oacc[0][nd] = mfma16(pa[0], vc[nd], oacc[0][nd]);
      oacc[1][nd] = mfma16(pa[1], vc[nd], oacc[1][nd]);
    }

#pragma unroll
    for (int i = 0; i < 4; ++i) kc[i] = kn[i];
  }

  // write pv (bf16, (b,h,i,d))
  ushort* po = pv + ((size_t)(b * 8 + h) * 1024 + i0) * 64;
#pragma unroll
  for (int mr = 0; mr < 2; ++mr)
#pragma unroll
    for (int nd = 0; nd < 4; ++nd)
#pragma unroll
      for (int r = 0; r < 4; ++r)
        po[(size_t)(mr * 16 + g4 * 4 + r) * 64 + nd * 16 + lr] = f2b(oacc[mr][nd][r]);
}

// ---------------- K3: out = pv(b,n,(h d)) @ W_out + b_out. 128x128 tile.
__global__ __launch_bounds__(256) void out_mfma(const ushort* __restrict__ pvb,
                                                const ushort* __restrict__ Wt,
                                                const float* __restrict__ bias,
                                                float* __restrict__ out) {
  __shared__ ushort A[128][40];
  __shared__ ushort Bs[128][40];
  const int tid = threadIdx.x;
  const int n0 = blockIdx.x * 128;
  const int m0 = blockIdx.y * 128;
  const int lane = tid & 63, wid = tid >> 6;
  const int wr = wid >> 1, wc = wid & 1;
  const int lr = lane & 15, g4 = lane >> 4;
  const int sr = tid >> 1, sco = (tid & 1) * 16;
  f32x4 acc[4][4] = {};
  for (int k0 = 0; k0 < 512; k0 += 32) {
    {
      int token = m0 + sr;
      int bi = token >> 10, ii = token & 1023;
      int f = k0 + sco;
      int hh = f >> 6, d = f & 63;
      const bf16x8* src =
          (const bf16x8*)&pvb[(((size_t)(bi * 8 + hh)) * 1024 + ii) * 64 + d];
      *(bf16x8*)&A[sr][sco] = src[0];
      *(bf16x8*)&A[sr][sco + 8] = src[1];
    }
    {
      const bf16x8* wp = (const bf16x8*)&Wt[(size_t)(n0 + sr) * 512 + k0 + sco];
      *(bf16x8*)&Bs[sr][sco] = wp[0];
      *(bf16x8*)&Bs[sr][sco + 8] = wp[1];
    }
    __syncthreads();
    bf16x8 af[4], bf[4];
#pragma unroll
    for (int mr = 0; mr < 4; ++mr) af[mr] = *(bf16x8*)&A[wr * 64 + mr * 16 + lr][g4 * 8];
#pragma unroll
    for (int nr = 0; nr < 4; ++nr) bf[nr] = *(bf16x8*)&Bs[wc * 64 + nr * 16 + lr][g4 * 8];
#pragma unroll
    for (int mr = 0; mr < 4; ++mr)
#pragma unroll
      for (int nr = 0; nr < 4; ++nr) acc[mr][nr] = mfma16(af[mr], bf[nr], acc[mr][nr]);
    __syncthreads();
  }
#pragma unroll
  for (int mr = 0; mr < 4; ++mr)
#pragma unroll
    for (int nr = 0; nr < 4; ++nr) {
      const int n = n0 + wc * 64 + nr * 16 + lr;
      const float bb = bias[n];
#pragma unroll
      for (int r = 0; r < 4; ++r) {
        int token = m0 + wr * 64 + mr * 16 + g4 * 4 + r;
        out[(size_t)token * 512 + n] = acc[mr][nr][r] + bb;
      }
    }
}

extern "C" void kernel_launch(void* const* d_in, const int* in_sizes, int n_in,
                              void* d_out, int out_size, void* d_ws, size_t ws_size,
                              hipStream_t stream) {
  const float* x    = (const float*)d_in[0];
  const float* Wqkv = (const float*)d_in[1];
  const float* bqkv = (const float*)d_in[2];
  const float* rw   = (const float*)d_in[3];
  const float* lng  = (const float*)d_in[4];
  const float* lnb  = (const float*)d_in[5];
  const float* Wout = (const float*)d_in[6];
  const float* bout = (const float*)d_in[7];

  float* out  = (float*)d_out;
  float* attn = (float*)d_out + 4194304;

  // ws: q [0,8M), k [8,16M), vt [16,24M), pvb [24,32M), Wqkvt [32,33.5M), Woutt [33.5,34M)
  char* wsb = (char*)d_ws;
  ushort* q     = (ushort*)(wsb);
  ushort* k     = (ushort*)(wsb + (8u << 20));
  ushort* vt    = (ushort*)(wsb + (16u << 20));
  ushort* pvb   = (ushort*)(wsb + (24u << 20));
  ushort* Wqkvt = (ushort*)(wsb + (32u << 20));
  ushort* Woutt = (ushort*)(wsb + (33u << 20) + (1u << 19));

  cast_transpose<<<dim3(24, 8), 256, 0, stream>>>(Wqkv, Wqkvt, 512, 1536);
  cast_transpose<<<dim3(8, 8), 256, 0, stream>>>(Wout, Woutt, 512, 512);

  qkv_mfma<<<dim3(12, 64), 256, 0, stream>>>(x, Wqkvt, bqkv, q, k, vt);
  attn_fused<<<dim3(256), 512, 0, stream>>>(q, k, vt, rw, lng, lnb, attn, pvb);
  out_mfma<<<dim3(4, 64), 256, 0, stream>>>(pvb, Woutt, bout, out);
}